// Round 5
// baseline (259.422 us; speedup 1.0000x reference)
//
#include <hip/hip_runtime.h>

// ts_zscore: rolling-window z-score
//   x: (B=64, T=4096, F=128) f32 ; out: (B=64, NK=4067, F=128) f32
//   out[b,k,f] = (x[b,k+29,f] - mean(x[b,k:k+30,f])) / (std(...) + 1e-4)
//
// R5: occupancy x2. R3/R4 latency-bound at 16 waves/CU (BW 34%, occ 35-38%,
// VALU 33%, ILP attempts collapsed by compiler). CH=32 -> 8192 waves =
// 32/CU (launch-side 100%); __launch_bounds__(256,8) pins VGPR<=64 (m69
// cliff). Overlap-pad removes the tail: every chunk is exactly 32 rows,
// no clamps/guards (final chunk rewrites a few rows with identical values).

#define B_DIM   64
#define T_DIM   4096
#define F_DIM   128
#define W_WIN   30
#define NK      4067      // T - W + 1
#define CH      32        // output rows per wave-chunk
#define CPB     128       // chunks per batch row = ceil(NK/CH)
#define EPS_Z   1e-4f

__global__ __launch_bounds__(256, 8)
void ts_zscore_kernel(const float* __restrict__ x, float* __restrict__ out) {
    // bijective XCD swizzle: 2048 blocks, 8 XCDs, 256 contiguous blocks/XCD
    int bid = (int)blockIdx.x;
    int cpx = (int)gridDim.x >> 3;            // 2048/8 = 256
    int swz = (bid & 7) * cpx + (bid >> 3);   // adjacent chunks -> same XCD

    int wave = (int)threadIdx.x >> 6;
    int lane = (int)threadIdx.x & 63;         // each lane owns 2 features (float2)

    int g  = swz * 4 + wave;                  // global chunk id, 0..8191
    int b  = g >> 7;                          // / CPB
    int c  = g & (CPB - 1);
    int k0 = c * CH;
    if (k0 > NK - CH) k0 = NK - CH;           // overlap-pad: all chunks full 32 rows

    const float2* __restrict__ xp =
        (const float2*)(x + (size_t)b * T_DIM * F_DIM) + (size_t)k0 * 64 + lane;
    float2* __restrict__ op =
        (float2*)(out + (size_t)b * NK * F_DIM) + (size_t)k0 * 64 + lane;

    // warm-up: sums over rows k0 .. k0+28
    float s1x = 0.f, s1y = 0.f, s2x = 0.f, s2y = 0.f;
    #pragma unroll
    for (int i = 0; i < 29; ++i) {
        float2 v = xp[i * 64];
        s1x += v.x;                s1y += v.y;
        s2x = fmaf(v.x, v.x, s2x); s2y = fmaf(v.y, v.y, s2y);
    }

    const float inv_w = 1.0f / (float)W_WIN;

    #pragma unroll 4
    for (int ss = 0; ss < CH; ++ss) {
        float2 v = xp[(29 + ss) * 64];   // newest row (streams from HBM/L3)
        float2 o = xp[ss * 64];          // oldest row (L1/L2-hot)

        float t1x = s1x + v.x,            t1y = s1y + v.y;
        float t2x = fmaf(v.x, v.x, s2x),  t2y = fmaf(v.y, v.y, s2y);

        float mx = t1x * inv_w,  my = t1y * inv_w;
        float vx = fmaxf(fmaf(-mx, mx, t2x * inv_w), 0.f);
        float vy = fmaxf(fmaf(-my, my, t2y * inv_w), 0.f);
        float ox = __fdividef(v.x - mx, __fsqrt_rn(vx) + EPS_Z);
        float oy = __fdividef(v.y - my, __fsqrt_rn(vy) + EPS_Z);
        op[ss * 64] = make_float2(ox, oy);

        s1x = t1x - o.x;          s1y = t1y - o.y;
        s2x = fmaf(-o.x, o.x, t2x); s2y = fmaf(-o.y, o.y, t2y);
    }
}

extern "C" void kernel_launch(void* const* d_in, const int* in_sizes, int n_in,
                              void* d_out, int out_size, void* d_ws, size_t ws_size,
                              hipStream_t stream) {
    const float* x = (const float*)d_in[0];
    float* out = (float*)d_out;
    dim3 grid((B_DIM * CPB) / 4);   // 2048 blocks of 4 waves, one chunk per wave
    dim3 block(256);
    ts_zscore_kernel<<<grid, block, 0, stream>>>(x, out);
}

// Round 7
// 238.060 us; speedup vs baseline: 1.0897x; 1.0897x over previous
//
#include <hip/hip_runtime.h>

// ts_zscore: rolling-window z-score
//   x: (B=64, T=4096, F=128) f32 ; out: (B=64, NK=4067, F=128) f32
//   out[b,k,f] = (x[b,k+29,f] - mean(x[b,k:k+30,f])) / (std(...) + 1e-4)
//
// R6: DRAM stream-granularity fix. R3/R4/R5 all pinned at ~2.7 TB/s regardless
// of occupancy/ILP -> pattern-limited, not latency-limited (~25k concurrent
// 512B-granule streams). Now: each block stages its whole 157-row input slab
// (80,384 B contiguous) into LDS via global_load_lds (20 rounds x 4KB, issued
// 20-deep before one syncthreads), compute reads v/o rows from LDS. Global
// reads become few long sequential streams; o-stream leaves global entirely.

#define B_DIM   64
#define T_DIM   4096
#define F_DIM   128
#define W_WIN   30
#define NK      4067               // T - W + 1
#define CH      128                // output rows per block
#define NCHUNK  32                 // ceil(NK/CH)
#define TROWS   157                // CH + W - 1 staged input rows
#define TILE_BYTES (TROWS * 512)   // 80,384 B  (2 blocks/CU: 160,768 <= 160 KiB)
#define ROUNDS  20                 // ceil(157 rows / 8 rows per 4KB round)
#define EPS_Z   1e-4f

__device__ __forceinline__ void gload_lds16(const float* g, float* l) {
    __builtin_amdgcn_global_load_lds(
        (const __attribute__((address_space(1))) void*)g,
        (__attribute__((address_space(3))) void*)l, 16, 0, 0);
}

__global__ __launch_bounds__(256)
void ts_zscore_kernel(const float* __restrict__ x, float* __restrict__ out) {
    extern __shared__ float smem[];            // [157][128] floats, linear

    // bijective XCD swizzle: 2048 blocks % 8 == 0, 256 contiguous chunks/XCD
    int bid = (int)blockIdx.x;
    int cpx = (int)gridDim.x >> 3;             // 256
    int swz = (bid & 7) * cpx + (bid >> 3);    // adjacent chunks -> same XCD

    int b  = swz >> 5;                          // / NCHUNK
    int c  = swz & (NCHUNK - 1);
    int k0 = c * CH; if (k0 > NK - CH) k0 = NK - CH;   // overlap-pad tail (max 3939)

    int tid  = (int)threadIdx.x;
    int wave = tid >> 6;
    int lane = tid & 63;

    const float* xb = x + (size_t)b * T_DIM * F_DIM;

    // ---- stage rows [k0, k0+157) -> LDS. Per round: 4KB contiguous (8 rows),
    // each wave one 1KB global_load_lds_dwordx4 slice. All 20 rounds in flight.
    #pragma unroll
    for (int q = 0; q < ROUNDS; ++q) {
        int tb = q * 4096 + wave * 1024 + lane * 16;   // tile byte offset
        if (tb < TILE_BYTES) {                          // mask tail of round 19
            int r = k0 + (tb >> 9);                     // global row
            if (r > T_DIM - 1) r = T_DIM - 1;           // belt-and-braces
            const float* gp = xb + ((size_t)r << 7) + ((tb & 511) >> 2);
            float* lp = smem + q * 1024 + wave * 256;   // wave-uniform LDS base
            gload_lds16(gp, lp);
        }
    }
    __syncthreads();   // compiler drains vmcnt(0) before s_barrier

    // ---- compute: wave w owns outputs [k0+32w, k0+32w+32); inputs rows
    // [32w, 32w+61) of the LDS tile. Rolling sums, all reads from LDS.
    const float2* lrow = (const float2*)smem;   // row r, lane: lrow[r*64 + lane]
    int base = wave * 32;
    float2* op = (float2*)(out + (size_t)b * NK * F_DIM)
               + (size_t)(k0 + base) * 64 + lane;

    float s1x = 0.f, s1y = 0.f, s2x = 0.f, s2y = 0.f;
    #pragma unroll
    for (int i = 0; i < 29; ++i) {
        float2 v = lrow[(base + i) * 64 + lane];
        s1x += v.x;                 s1y += v.y;
        s2x = fmaf(v.x, v.x, s2x);  s2y = fmaf(v.y, v.y, s2y);
    }

    const float inv_w = 1.0f / (float)W_WIN;

    #pragma unroll 8
    for (int ss = 0; ss < 32; ++ss) {
        float2 v = lrow[(base + 29 + ss) * 64 + lane];
        float2 o = lrow[(base + ss) * 64 + lane];

        float t1x = s1x + v.x,             t1y = s1y + v.y;
        float t2x = fmaf(v.x, v.x, s2x),   t2y = fmaf(v.y, v.y, s2y);

        float mx = t1x * inv_w,  my = t1y * inv_w;
        float vx = fmaxf(fmaf(-mx, mx, t2x * inv_w), 0.f);
        float vy = fmaxf(fmaf(-my, my, t2y * inv_w), 0.f);
        float ox = __fdividef(v.x - mx, __fsqrt_rn(vx) + EPS_Z);
        float oy = __fdividef(v.y - my, __fsqrt_rn(vy) + EPS_Z);
        op[ss * 64] = make_float2(ox, oy);

        s1x = t1x - o.x;            s1y = t1y - o.y;
        s2x = fmaf(-o.x, o.x, t2x); s2y = fmaf(-o.y, o.y, t2y);
    }
}

extern "C" void kernel_launch(void* const* d_in, const int* in_sizes, int n_in,
                              void* d_out, int out_size, void* d_ws, size_t ws_size,
                              hipStream_t stream) {
    const float* x = (const float*)d_in[0];
    float* out = (float*)d_out;
    dim3 grid(B_DIM * NCHUNK);    // 2048 blocks, one 128-row chunk each
    dim3 block(256);
    ts_zscore_kernel<<<grid, block, TILE_BYTES, stream>>>(x, out);
}